// Round 4
// baseline (1570.196 us; speedup 1.0000x reference)
//
#include <hip/hip_runtime.h>

#define TOKS 49
#define DIM_ 384
#define NHEAD 12
#define HDIM 32

typedef short bf16x8 __attribute__((ext_vector_type(8)));
typedef float f32x4 __attribute__((ext_vector_type(4)));

// LDS strides (elements). All row strides are multiples of 8 elems (16B) and
// chosen so ds_read_b128 across 16 rows aliases <=2 lanes/bank (free).
#define SXA 392   // xA / Obuf: 64 x 392
#define SQK 136   // Q4 / K4:   64 x 136 (4 heads * 32 + 8 pad)
#define SV   72   // Vt4:      128 x 72  (row = head'*32+d, col = token)
#define SS   72   // Sbf:       64 x 72

#define LDS_ELEMS (64*SXA + 64*SQK + 64*SQK + 128*SV + 64*SS + 64*SXA)
#define LDS_BYTES (LDS_ELEMS*2)   // 162816 <= 163840

#define WS_NEEDED ((size_t)(3*DIM_*DIM_ + DIM_*DIM_)*2 + (size_t)NHEAD*TOKS*TOKS*4)

__device__ __forceinline__ unsigned short f2b(float f) {
  union { float f; unsigned u; } x; x.f = f;
  return (unsigned short)((x.u + 0x7FFFu + ((x.u >> 16) & 1u)) >> 16);  // RNE
}

// Pack weights into B-fragment-major bf16 layout:
// frag (ct, kk): lane l, elem j  <-  W[ct*16 + (l&15)][kk*32 + (l>>4)*8 + j]
// so a B-frag load is 64 lanes x consecutive 16B = one coalesced 1KB read.
__global__ void prep_kernel(const float* __restrict__ qkv_w,
                            const float* __restrict__ proj_w,
                            const float* __restrict__ rpb,
                            unsigned short* __restrict__ w1p,
                            unsigned short* __restrict__ w2p,
                            float* __restrict__ biasM) {
  int i = blockIdx.x * 256 + threadIdx.x;
  if (i < 3*DIM_*DIM_) {
    int j = i & 7, l = (i >> 3) & 63, rest = i >> 9;
    int kk = rest % 12, ct = rest / 12;
    int row = ct*16 + (l & 15);
    int k = kk*32 + ((l >> 4) << 3) + j;
    w1p[i] = f2b(qkv_w[row*DIM_ + k]);
  }
  if (i < DIM_*DIM_) {
    int j = i & 7, l = (i >> 3) & 63, rest = i >> 9;
    int kk = rest % 12, ct = rest / 12;
    int row = ct*16 + (l & 15);
    int k = kk*32 + ((l >> 4) << 3) + j;
    w2p[i] = f2b(proj_w[row*DIM_ + k]);
  }
  if (i < NHEAD*TOKS*TOKS) {
    int h = i / (TOKS*TOKS);
    int rem = i % (TOKS*TOKS);
    int r = rem / TOKS, c = rem % TOKS;
    int idx = (r/7 - c/7 + 6)*13 + (r%7 - c%7 + 6);
    biasM[i] = rpb[idx*NHEAD + h];
  }
}

__global__ __launch_bounds__(512, 2)
void wattn_kernel(const float* __restrict__ x,
                  const float* __restrict__ mask,
                  const unsigned short* __restrict__ w1p,
                  const float* __restrict__ b1,
                  const unsigned short* __restrict__ w2p,
                  const float* __restrict__ b2,
                  const float* __restrict__ biasM,
                  float* __restrict__ out) {
  extern __shared__ unsigned short lds[];
  unsigned short* xA  = lds;            // x tile, bf16, rows 49..63 zeroed
  unsigned short* Q4  = xA + 64*SXA;    // q (pre-scaled) for 4 heads
  unsigned short* K4  = Q4 + 64*SQK;    // k for 4 heads
  unsigned short* Vt4 = K4 + 64*SQK;    // v transposed for 4 heads
  unsigned short* Sbf = Vt4 + 128*SV;   // softmaxed P (bf16), cols>=49 zero
  unsigned short* Ob  = Sbf + 64*SS;    // attention output (all 12 heads)

  const int tid = threadIdx.x;
  const int lane = tid & 63;
  const int wv = tid >> 6;
  const int lr = lane & 15;   // row-of-A / col-of-B / col-of-D selector
  const int lg = lane >> 4;   // k-group; D rows = 4*lg + j
  const int b  = blockIdx.x;
  const int wi = b & 63;

  // ---- stage x -> bf16 LDS (64 rows, rows >=49 zero)
  {
    const float* xg = x + (size_t)b * TOKS * DIM_;
    for (int idx = tid; idx < TOKS*48; idx += 512) {
      int r = idx / 48, c8 = (idx % 48) << 3;
      const float4* p = (const float4*)(xg + r*DIM_ + c8);
      float4 a0 = p[0], a1 = p[1];
      bf16x8 v;
      v[0]=(short)f2b(a0.x); v[1]=(short)f2b(a0.y); v[2]=(short)f2b(a0.z); v[3]=(short)f2b(a0.w);
      v[4]=(short)f2b(a1.x); v[5]=(short)f2b(a1.y); v[6]=(short)f2b(a1.z); v[7]=(short)f2b(a1.w);
      *(bf16x8*)&xA[r*SXA + c8] = v;
    }
    bf16x8 z = {0,0,0,0,0,0,0,0};
    for (int idx = tid; idx < 15*48; idx += 512) {
      int r = 49 + idx / 48, c8 = (idx % 48) << 3;
      *(bf16x8*)&xA[r*SXA + c8] = z;
    }
  }
  __syncthreads();

  const f32x4 fz = {0.f, 0.f, 0.f, 0.f};

  for (int g = 0; g < 3; ++g) {
    const int hbase = g * 4;

    // ---- GEMM1: qkv for 4 heads (64 x 384 output = 24 n-tiles, 3 per wave)
    #pragma unroll
    for (int ni = 0; ni < 3; ++ni) {
      const int nt = wv + ni*8;
      const int p = nt >> 3;                       // 0=q 1=k 2=v
      const int ct = p*24 + hbase*2 + (nt & 7);    // 16-channel block id
      const int d128 = ((nt & 7) << 4) + lr;       // channel within 4-head group
      const unsigned short* bp = w1p + ((size_t)(ct*12)*64 + lane)*8;
      f32x4 acc[4];
      #pragma unroll
      for (int m = 0; m < 4; ++m) acc[m] = fz;
      #pragma unroll
      for (int kk = 0; kk < 12; ++kk) {
        bf16x8 bf = *(const bf16x8*)(bp + kk*512);
        #pragma unroll
        for (int m = 0; m < 4; ++m) {
          bf16x8 af = *(const bf16x8*)&xA[(m*16 + lr)*SXA + kk*32 + lg*8];
          acc[m] = __builtin_amdgcn_mfma_f32_16x16x32_bf16(af, bf, acc[m], 0, 0, 0);
        }
      }
      const float bias = b1[ct*16 + lr];
      #pragma unroll
      for (int m = 0; m < 4; ++m) {
        #pragma unroll
        for (int j = 0; j < 4; ++j) {
          float v = acc[m][j] + bias;
          int tok = m*16 + lg*4 + j;
          if (p == 0)      Q4[tok*SQK + d128] = f2b(v * 0.17677669529663687f);
          else if (p == 1) K4[tok*SQK + d128] = f2b(v);
          else             Vt4[d128*SV + tok] = f2b(v);
        }
      }
    }
    __syncthreads();

    for (int hh = 0; hh < 4; ++hh) {
      const int h = hbase + hh;
      const int qoff = hh * HDIM;

      // ---- QK^T + softmax (waves 0..3, wave w owns rows 16w..16w+15)
      if (wv < 4) {
        const int m0 = wv << 4;
        bf16x8 qa = *(const bf16x8*)&Q4[(m0 + lr)*SQK + qoff + lg*8];
        f32x4 S[4];
        #pragma unroll
        for (int nt = 0; nt < 4; ++nt) {
          bf16x8 kb = *(const bf16x8*)&K4[((nt<<4) + lr)*SQK + qoff + lg*8];
          S[nt] = __builtin_amdgcn_mfma_f32_16x16x32_bf16(qa, kb, fz, 0, 0, 0);
        }
        #pragma unroll
        for (int j = 0; j < 4; ++j) {
          const int r_ = m0 + lg*4 + j;
          float lv[4];
          float mx = -1e30f;
          #pragma unroll
          for (int nt = 0; nt < 4; ++nt) {
            const int c_ = (nt<<4) + lr;
            float v = S[nt][j];
            if (r_ < TOKS && c_ < TOKS)
              v += biasM[(h*TOKS + r_)*TOKS + c_] + mask[((size_t)wi*TOKS + r_)*TOKS + c_];
            if (c_ >= TOKS) v = -1e30f;
            lv[nt] = v;
            mx = fmaxf(mx, v);
          }
          mx = fmaxf(mx, __shfl_xor(mx, 1));
          mx = fmaxf(mx, __shfl_xor(mx, 2));
          mx = fmaxf(mx, __shfl_xor(mx, 4));
          mx = fmaxf(mx, __shfl_xor(mx, 8));
          float sum = 0.f;
          #pragma unroll
          for (int nt = 0; nt < 4; ++nt) {
            float e = (((nt<<4) + lr) >= TOKS) ? 0.f : __expf(lv[nt] - mx);
            lv[nt] = e; sum += e;
          }
          sum += __shfl_xor(sum, 1);
          sum += __shfl_xor(sum, 2);
          sum += __shfl_xor(sum, 4);
          sum += __shfl_xor(sum, 8);
          const float inv = 1.0f / sum;
          #pragma unroll
          for (int nt = 0; nt < 4; ++nt)
            Sbf[r_*SS + (nt<<4) + lr] = f2b(lv[nt] * inv);
        }
      }
      __syncthreads();

      // ---- PV: O(64x32) = P(64x64) @ V(64x32); 8 tiles, 1 per wave
      {
        const int m0 = (wv >> 1) << 4;
        const int d0 = (wv & 1) << 4;
        f32x4 o = fz;
        #pragma unroll
        for (int kk = 0; kk < 2; ++kk) {
          bf16x8 sa = *(const bf16x8*)&Sbf[(m0 + lr)*SS + kk*32 + lg*8];
          bf16x8 vb = *(const bf16x8*)&Vt4[(qoff + d0 + lr)*SV + kk*32 + lg*8];
          o = __builtin_amdgcn_mfma_f32_16x16x32_bf16(sa, vb, o, 0, 0, 0);
        }
        const int col = h*HDIM + d0 + lr;
        #pragma unroll
        for (int j = 0; j < 4; ++j) {
          int tok = m0 + lg*4 + j;
          Ob[tok*SXA + col] = f2b(o[j]);
        }
      }
      __syncthreads();
    }
  }

  // ---- GEMM2: out = O @ proj_w^T + proj_b
  #pragma unroll
  for (int ni = 0; ni < 3; ++ni) {
    const int nt = wv + ni*8;
    const int col = (nt << 4) + lr;
    const unsigned short* bp = w2p + ((size_t)(nt*12)*64 + lane)*8;
    f32x4 acc[4];
    #pragma unroll
    for (int m = 0; m < 4; ++m) acc[m] = fz;
    #pragma unroll
    for (int kk = 0; kk < 12; ++kk) {
      bf16x8 bf = *(const bf16x8*)(bp + kk*512);
      #pragma unroll
      for (int m = 0; m < 4; ++m) {
        bf16x8 af = *(const bf16x8*)&Ob[(m*16 + lr)*SXA + kk*32 + lg*8];
        acc[m] = __builtin_amdgcn_mfma_f32_16x16x32_bf16(af, bf, acc[m], 0, 0, 0);
      }
    }
    const float pb = b2[col];
    float* og = out + (size_t)b * TOKS * DIM_;
    #pragma unroll
    for (int m = 0; m < 4; ++m) {
      #pragma unroll
      for (int j = 0; j < 4; ++j) {
        const int tok = m*16 + lg*4 + j;
        if (tok < TOKS) og[tok*DIM_ + col] = acc[m][j] + pb;
      }
    }
  }
}

extern "C" void kernel_launch(void* const* d_in, const int* in_sizes, int n_in,
                              void* d_out, int out_size, void* d_ws, size_t ws_size,
                              hipStream_t stream) {
  const float* x      = (const float*)d_in[0];
  const float* mask   = (const float*)d_in[1];
  const float* qkv_w  = (const float*)d_in[2];
  const float* qkv_b  = (const float*)d_in[3];
  const float* proj_w = (const float*)d_in[4];
  const float* proj_b = (const float*)d_in[5];
  const float* rpb    = (const float*)d_in[6];
  float* out = (float*)d_out;

  if (ws_size < WS_NEEDED) return;  // refuse to fault on undersized workspace

  unsigned short* w1p = (unsigned short*)d_ws;          // 442368 bf16
  unsigned short* w2p = w1p + 3*DIM_*DIM_;              // 147456 bf16
  float* biasM = (float*)(w2p + DIM_*DIM_);             // 12*49*49 f32

  prep_kernel<<<1728, 256, 0, stream>>>(qkv_w, proj_w, rpb, w1p, w2p, biasM);

  hipFuncSetAttribute((const void*)wattn_kernel,
                      hipFuncAttributeMaxDynamicSharedMemorySize, LDS_BYTES);
  wattn_kernel<<<4096, 512, LDS_BYTES, stream>>>(x, mask, w1p, qkv_b, w2p,
                                                 proj_b, biasM, out);
}

// Round 5
// 627.717 us; speedup vs baseline: 2.5014x; 2.5014x over previous
//
#include <hip/hip_runtime.h>

#define TOKS 49
#define DIM_ 384
#define NHEAD 12
#define HDIM 32

typedef short bf16x8 __attribute__((ext_vector_type(8)));
typedef float f32x4 __attribute__((ext_vector_type(4)));

// LDS strides (elements). Row strides chosen so b128 frag reads are at the
// 8-accesses/bank minimum (stride%32dw==4 patterns).
#define SXA 392   // xA / Ob: 64 x 392
#define SQK 136   // Q4 / K4: 64 x 136 (4 heads * 32 + 8 pad)
#define SV   72   // Vt4:    128 x 72  (row = head'*32+d, col = token)

#define LDS_ELEMS (64*SXA + 64*SQK + 64*SQK + 128*SV + 64*SXA)
#define LDS_BYTES (LDS_ELEMS*2)   // 153600 <= 163840

#define W1E (3*DIM_*DIM_)         // 442368 bf16
#define W2E (DIM_*DIM_)           // 147456 bf16
#define CMBE (64*NHEAD*64*64)     // 3145728 f32
#define WS_NEEDED ((size_t)(W1E+W2E)*2 + (size_t)CMBE*4)

__device__ __forceinline__ unsigned short f2b(float f) {
  union { float f; unsigned u; } x; x.f = f;
  return (unsigned short)((x.u + 0x7FFFu + ((x.u >> 16) & 1u)) >> 16);  // RNE
}

// w1p/w2p: B-fragment-major bf16: frag (ct,kk): lane l, elem j <-
//   W[ct*16 + (l&15)][kk*32 + (l>>4)*8 + j]  (one frag = coalesced 1KB)
// CmbT[wi][h][k][q] (64x64, padded): bias[h][q][k] + mask[wi][q][k], or -1e30
// outside the valid 49x49 region (drives masked P to exactly 0).
__global__ void prep_kernel(const float* __restrict__ qkv_w,
                            const float* __restrict__ proj_w,
                            const float* __restrict__ rpb,
                            const float* __restrict__ mask,
                            unsigned short* __restrict__ w1p,
                            unsigned short* __restrict__ w2p,
                            float* __restrict__ cmb) {
  int i = blockIdx.x * 256 + threadIdx.x;
  if (i < W1E) {
    int j = i & 7, l = (i >> 3) & 63, rest = i >> 9;
    int kk = rest % 12, ct = rest / 12;
    w1p[i] = f2b(qkv_w[(ct*16 + (l & 15))*DIM_ + kk*32 + ((l >> 4) << 3) + j]);
  }
  if (i < W2E) {
    int j = i & 7, l = (i >> 3) & 63, rest = i >> 9;
    int kk = rest % 12, ct = rest / 12;
    w2p[i] = f2b(proj_w[(ct*16 + (l & 15))*DIM_ + kk*32 + ((l >> 4) << 3) + j]);
  }
  if (i < CMBE) {
    int q = i & 63, k = (i >> 6) & 63, hw = i >> 12;
    int h = hw % 12, wi = hw / 12;
    float v = -1e30f;
    if (q < TOKS && k < TOKS) {
      int idx = (q/7 - k/7 + 6)*13 + (q%7 - k%7 + 6);
      v = rpb[idx*NHEAD + h] + mask[((size_t)wi*TOKS + q)*TOKS + k];
    }
    cmb[i] = v;
  }
}

__global__ __launch_bounds__(512, 2)
void wattn_kernel(const float* __restrict__ x,
                  const unsigned short* __restrict__ w1p,
                  const float* __restrict__ b1,
                  const unsigned short* __restrict__ w2p,
                  const float* __restrict__ b2,
                  const float* __restrict__ cmb,
                  float* __restrict__ out) {
  extern __shared__ unsigned short lds[];
  unsigned short* xA  = lds;            // x tile bf16, rows 49..63 zeroed
  unsigned short* Q4  = xA + 64*SXA;    // q (pre-scaled), 4 heads
  unsigned short* K4  = Q4 + 64*SQK;    // k, 4 heads
  unsigned short* Vt4 = K4 + 64*SQK;    // v transposed, 4 heads
  unsigned short* Ob  = Vt4 + 128*SV;   // attention output (12 heads)

  const int tid  = threadIdx.x;
  const int lane = tid & 63;
  const int wv   = tid >> 6;
  const int lr   = lane & 15;
  const int lg   = lane >> 4;
  const int b    = blockIdx.x;
  const int wi   = b & 63;

  // ---- stage x -> bf16 LDS (64 rows, rows >=49 zero)
  {
    const float* xg = x + (size_t)b * TOKS * DIM_;
    for (int idx = tid; idx < TOKS*48; idx += 512) {
      int r = idx / 48, c8 = (idx % 48) << 3;
      const float4* p = (const float4*)(xg + r*DIM_ + c8);
      float4 a0 = p[0], a1 = p[1];
      bf16x8 v;
      v[0]=(short)f2b(a0.x); v[1]=(short)f2b(a0.y); v[2]=(short)f2b(a0.z); v[3]=(short)f2b(a0.w);
      v[4]=(short)f2b(a1.x); v[5]=(short)f2b(a1.y); v[6]=(short)f2b(a1.z); v[7]=(short)f2b(a1.w);
      *(bf16x8*)&xA[r*SXA + c8] = v;
    }
    bf16x8 z = {0,0,0,0,0,0,0,0};
    for (int idx = tid; idx < 15*48; idx += 512) {
      int r = 49 + idx / 48, c8 = (idx % 48) << 3;
      *(bf16x8*)&xA[r*SXA + c8] = z;
    }
  }
  __syncthreads();

  const f32x4 fz = {0.f, 0.f, 0.f, 0.f};

  for (int g = 0; g < 3; ++g) {
    const int hbase = g * 4;

    // ---- GEMM1: qkv for 4 heads. Wave wv owns 16-col block (hbase*2+wv) of
    // each of q/k/v; A-frags loaded once per (kk,m) and reused 3x.
    {
      const int cb = hbase*2 + wv;
      const unsigned short* bq = w1p + (size_t)(cb*12)*512 + lane*8;
      const unsigned short* bk = bq + (size_t)(24*12)*512;
      const unsigned short* bv = bq + (size_t)(48*12)*512;
      f32x4 aq[4], ak[4], av[4];
      #pragma unroll
      for (int m = 0; m < 4; ++m) { aq[m]=fz; ak[m]=fz; av[m]=fz; }
      #pragma unroll
      for (int kk = 0; kk < 12; ++kk) {
        bf16x8 fq = *(const bf16x8*)(bq + kk*512);
        bf16x8 fk = *(const bf16x8*)(bk + kk*512);
        bf16x8 fv = *(const bf16x8*)(bv + kk*512);
        #pragma unroll
        for (int m = 0; m < 4; ++m) {
          bf16x8 a = *(const bf16x8*)&xA[(m*16 + lr)*SXA + kk*32 + lg*8];
          aq[m] = __builtin_amdgcn_mfma_f32_16x16x32_bf16(a, fq, aq[m], 0, 0, 0);
          ak[m] = __builtin_amdgcn_mfma_f32_16x16x32_bf16(a, fk, ak[m], 0, 0, 0);
          av[m] = __builtin_amdgcn_mfma_f32_16x16x32_bf16(a, fv, av[m], 0, 0, 0);
        }
      }
      const float bsq = b1[cb*16 + lr];
      const float bsk = b1[(24 + cb)*16 + lr];
      const float bsv = b1[(48 + cb)*16 + lr];
      const int d128 = (wv << 4) + lr;
      #pragma unroll
      for (int m = 0; m < 4; ++m) {
        #pragma unroll
        for (int j = 0; j < 4; ++j) {
          const int tok = m*16 + lg*4 + j;
          Q4[tok*SQK + d128]  = f2b((aq[m][j] + bsq) * 0.17677669529663687f);
          K4[tok*SQK + d128]  = f2b(ak[m][j] + bsk);
          Vt4[d128*SV + tok]  = f2b(av[m][j] + bsv);
        }
      }
    }
    __syncthreads();

    // ---- attention: 2 heads per pass, all 8 waves, softmax in-register.
    // Wave: head = hbase + hp*2 + (wv>>2), q-rows m0 = (wv&3)*16.
    #pragma unroll
    for (int hp = 0; hp < 2; ++hp) {
      const int hl = hp*2 + (wv >> 2);
      const int h  = hbase + hl;
      const int qoff = hl * HDIM;
      const int m0 = (wv & 3) << 4;

      // hoist combined bias+mask loads (independent of QK^T)
      float c[4][4];
      const float* cp = cmb + ((size_t)(wi*NHEAD + h) << 12) + m0 + lr;
      #pragma unroll
      for (int nt = 0; nt < 4; ++nt)
        #pragma unroll
        for (int jj = 0; jj < 4; ++jj)
          c[nt][jj] = cp[(nt*16 + lg*4 + jj) << 6];

      // swapped QK^T: S^T[k][q] = mfma(A=K, B=Q); lane holds 16 k's of col q
      bf16x8 qa = *(const bf16x8*)&Q4[(m0 + lr)*SQK + qoff + lg*8];
      f32x4 S[4];
      #pragma unroll
      for (int nt = 0; nt < 4; ++nt) {
        bf16x8 kb = *(const bf16x8*)&K4[((nt<<4) + lr)*SQK + qoff + lg*8];
        S[nt] = __builtin_amdgcn_mfma_f32_16x16x32_bf16(kb, qa, fz, 0, 0, 0);
      }

      // softmax over k (lanes lr, lr+16, lr+32, lr+48 share column q)
      float p[4][4];
      float mx = -1e30f;
      #pragma unroll
      for (int nt = 0; nt < 4; ++nt)
        #pragma unroll
        for (int jj = 0; jj < 4; ++jj) {
          p[nt][jj] = S[nt][jj] + c[nt][jj];
          mx = fmaxf(mx, p[nt][jj]);
        }
      mx = fmaxf(mx, __shfl_xor(mx, 16));
      mx = fmaxf(mx, __shfl_xor(mx, 32));
      float sum = 0.f;
      #pragma unroll
      for (int nt = 0; nt < 4; ++nt)
        #pragma unroll
        for (int jj = 0; jj < 4; ++jj) {
          float e = __expf(p[nt][jj] - mx);
          p[nt][jj] = e; sum += e;
        }
      sum += __shfl_xor(sum, 16);
      sum += __shfl_xor(sum, 32);
      const float inv = 1.0f / sum;

      // pack P to bf16 pairs (per nt: (p0,p1),(p2,p3))
      unsigned pk[4][2];
      #pragma unroll
      for (int nt = 0; nt < 4; ++nt) {
        pk[nt][0] = (unsigned)f2b(p[nt][0]*inv) | ((unsigned)f2b(p[nt][1]*inv) << 16);
        pk[nt][1] = (unsigned)f2b(p[nt][2]*inv) | ((unsigned)f2b(p[nt][3]*inv) << 16);
      }

      // PV: O[q][d] = sum_k P^T[k][q] V[k][d]. Assemble A-frags (rows=q) by
      // cross-lg shuffles; shuffled register index is uniform (two-shfl+select).
      const int src0 = (lane & 15) + ((lane & 16) << 1);
      const int src1 = src0 + 16;
      const bool loH = lane < 32;   // lg<2 -> k-block 2kk, else 2kk+1
      f32x4 o0 = fz, o1 = fz;
      #pragma unroll
      for (int kk = 0; kk < 2; ++kk) {
        unsigned wA0 = __shfl(pk[2*kk][0], src0), wB0 = __shfl(pk[2*kk+1][0], src0);
        unsigned wA1 = __shfl(pk[2*kk][1], src0), wB1 = __shfl(pk[2*kk+1][1], src0);
        unsigned wA2 = __shfl(pk[2*kk][0], src1), wB2 = __shfl(pk[2*kk+1][0], src1);
        unsigned wA3 = __shfl(pk[2*kk][1], src1), wB3 = __shfl(pk[2*kk+1][1], src1);
        union { unsigned u[4]; bf16x8 v; } af;
        af.u[0] = loH ? wA0 : wB0;
        af.u[1] = loH ? wA1 : wB1;
        af.u[2] = loH ? wA2 : wB2;
        af.u[3] = loH ? wA3 : wB3;
        bf16x8 vb0 = *(const bf16x8*)&Vt4[(qoff + lr)*SV + kk*32 + lg*8];
        bf16x8 vb1 = *(const bf16x8*)&Vt4[(qoff + 16 + lr)*SV + kk*32 + lg*8];
        o0 = __builtin_amdgcn_mfma_f32_16x16x32_bf16(af.v, vb0, o0, 0, 0, 0);
        o1 = __builtin_amdgcn_mfma_f32_16x16x32_bf16(af.v, vb1, o1, 0, 0, 0);
      }
      const int ocol = h*HDIM + lr;
      #pragma unroll
      for (int j = 0; j < 4; ++j) {
        const int tok = m0 + lg*4 + j;
        Ob[tok*SXA + ocol]      = f2b(o0[j]);
        Ob[tok*SXA + ocol + 16] = f2b(o1[j]);
      }
    }
    __syncthreads();
  }

  // ---- GEMM2: out = O @ proj_w^T + proj_b (A-frags reused over 3 n-tiles)
  {
    const unsigned short* bp0 = w2p + (size_t)(wv*12)*512 + lane*8;
    const unsigned short* bp1 = bp0 + (size_t)(8*12)*512;
    const unsigned short* bp2 = bp0 + (size_t)(16*12)*512;
    f32x4 ac0[4], ac1[4], ac2[4];
    #pragma unroll
    for (int m = 0; m < 4; ++m) { ac0[m]=fz; ac1[m]=fz; ac2[m]=fz; }
    #pragma unroll
    for (int kk = 0; kk < 12; ++kk) {
      bf16x8 f0 = *(const bf16x8*)(bp0 + kk*512);
      bf16x8 f1 = *(const bf16x8*)(bp1 + kk*512);
      bf16x8 f2 = *(const bf16x8*)(bp2 + kk*512);
      #pragma unroll
      for (int m = 0; m < 4; ++m) {
        bf16x8 a = *(const bf16x8*)&Ob[(m*16 + lr)*SXA + kk*32 + lg*8];
        ac0[m] = __builtin_amdgcn_mfma_f32_16x16x32_bf16(a, f0, ac0[m], 0, 0, 0);
        ac1[m] = __builtin_amdgcn_mfma_f32_16x16x32_bf16(a, f1, ac1[m], 0, 0, 0);
        ac2[m] = __builtin_amdgcn_mfma_f32_16x16x32_bf16(a, f2, ac2[m], 0, 0, 0);
      }
    }
    float* og = out + (size_t)b * TOKS * DIM_;
    #pragma unroll
    for (int ni = 0; ni < 3; ++ni) {
      const int col = ((wv + ni*8) << 4) + lr;
      const float pb = b2[col];
      const f32x4* ac = ni == 0 ? ac0 : (ni == 1 ? ac1 : ac2);
      #pragma unroll
      for (int m = 0; m < 4; ++m)
        #pragma unroll
        for (int j = 0; j < 4; ++j) {
          const int tok = m*16 + lg*4 + j;
          if (tok < TOKS) og[tok*DIM_ + col] = ac[m][j] + pb;
        }
    }
  }
}

extern "C" void kernel_launch(void* const* d_in, const int* in_sizes, int n_in,
                              void* d_out, int out_size, void* d_ws, size_t ws_size,
                              hipStream_t stream) {
  const float* x      = (const float*)d_in[0];
  const float* mask   = (const float*)d_in[1];
  const float* qkv_w  = (const float*)d_in[2];
  const float* qkv_b  = (const float*)d_in[3];
  const float* proj_w = (const float*)d_in[4];
  const float* proj_b = (const float*)d_in[5];
  const float* rpb    = (const float*)d_in[6];
  float* out = (float*)d_out;

  if (ws_size < WS_NEEDED) return;  // refuse to fault on undersized workspace

  unsigned short* w1p = (unsigned short*)d_ws;
  unsigned short* w2p = w1p + W1E;
  float* cmb = (float*)(w2p + W2E);

  prep_kernel<<<(CMBE + 255)/256, 256, 0, stream>>>(qkv_w, proj_w, rpb, mask,
                                                    w1p, w2p, cmb);

  hipFuncSetAttribute((const void*)wattn_kernel,
                      hipFuncAttributeMaxDynamicSharedMemorySize, LDS_BYTES);
  wattn_kernel<<<4096, 512, LDS_BYTES, stream>>>(x, w1p, qkv_b, w2p,
                                                 proj_b, cmb, out);
}

// Round 6
// 597.781 us; speedup vs baseline: 2.6267x; 1.0501x over previous
//
#include <hip/hip_runtime.h>

#define TOKS 49
#define DIM_ 384
#define NHEAD 12
#define HDIM 32

typedef short bf16x8 __attribute__((ext_vector_type(8)));
typedef float f32x4 __attribute__((ext_vector_type(4)));

#define SXA 392   // xA / Ob: 64 x 392
#define SQK 136   // Q4 / K4: 64 x 136 (4 heads * 32 + 8 pad)
#define SV   72   // Vt4:    128 x 72  (row = head'*32+d, col = token)

#define LDS_ELEMS (64*SXA + 64*SQK + 64*SQK + 128*SV + 64*SXA)
#define LDS_BYTES (LDS_ELEMS*2)   // 153600 <= 163840

#define W1E (3*DIM_*DIM_)         // 442368 bf16
#define W2E (DIM_*DIM_)           // 147456 bf16
#define CMBE (64*NHEAD*64*64)     // 3145728 f32
#define WS_NEEDED ((size_t)(W1E+W2E)*2 + (size_t)CMBE*4)

__device__ __forceinline__ unsigned short f2b(float f) {
  union { float f; unsigned u; } x; x.f = f;
  return (unsigned short)((x.u + 0x7FFFu + ((x.u >> 16) & 1u)) >> 16);  // RNE
}

// w1p/w2p: B-fragment-major bf16: frag (ct,kk): lane l, elem j <-
//   W[ct*16 + (l&15)][kk*32 + (l>>4)*8 + j]  (one frag = coalesced 1KB)
// CmbT[wi][h][k][q] (64x64, padded): bias[h][q][k] + mask[wi][q][k], or -1e30
// outside the valid 49x49 region (drives masked P to exactly 0).
__global__ void prep_kernel(const float* __restrict__ qkv_w,
                            const float* __restrict__ proj_w,
                            const float* __restrict__ rpb,
                            const float* __restrict__ mask,
                            unsigned short* __restrict__ w1p,
                            unsigned short* __restrict__ w2p,
                            float* __restrict__ cmb) {
  int i = blockIdx.x * 256 + threadIdx.x;
  if (i < W1E) {
    int j = i & 7, l = (i >> 3) & 63, rest = i >> 9;
    int kk = rest % 12, ct = rest / 12;
    w1p[i] = f2b(qkv_w[(ct*16 + (l & 15))*DIM_ + kk*32 + ((l >> 4) << 3) + j]);
  }
  if (i < W2E) {
    int j = i & 7, l = (i >> 3) & 63, rest = i >> 9;
    int kk = rest % 12, ct = rest / 12;
    w2p[i] = f2b(proj_w[(ct*16 + (l & 15))*DIM_ + kk*32 + ((l >> 4) << 3) + j]);
  }
  if (i < CMBE) {
    int q = i & 63, k = (i >> 6) & 63, hw = i >> 12;
    int h = hw % 12, wi = hw / 12;
    float v = -1e30f;
    if (q < TOKS && k < TOKS) {
      int idx = (q/7 - k/7 + 6)*13 + (q%7 - k%7 + 6);
      v = rpb[idx*NHEAD + h] + mask[((size_t)wi*TOKS + q)*TOKS + k];
    }
    cmb[i] = v;
  }
}

__global__ __launch_bounds__(1024, 1)
void wattn_kernel(const float* __restrict__ x,
                  const unsigned short* __restrict__ w1p,
                  const float* __restrict__ b1,
                  const unsigned short* __restrict__ w2p,
                  const float* __restrict__ b2,
                  const float* __restrict__ cmb,
                  float* __restrict__ out) {
  extern __shared__ unsigned short lds[];
  unsigned short* xA  = lds;            // x tile bf16, rows 49..63 zeroed
  unsigned short* Q4  = xA + 64*SXA;    // q (pre-scaled), 4 heads
  unsigned short* K4  = Q4 + 64*SQK;    // k, 4 heads
  unsigned short* Vt4 = K4 + 64*SQK;    // v transposed, 4 heads
  unsigned short* Ob  = Vt4 + 128*SV;   // attention output (12 heads)

  const int tid  = threadIdx.x;
  const int lane = tid & 63;
  const int wv   = tid >> 6;            // 0..15
  const int lr   = lane & 15;
  const int lg   = lane >> 4;
  const int b    = blockIdx.x;
  const int wi   = b & 63;

  const int mh    = wv & 1;             // m-half for GEMM1/GEMM2
  const int ctile = wv >> 1;            // 0..7 col-tile

  // ---- stage x -> bf16 LDS (64 rows, rows >=49 zero)
  {
    const float* xg = x + (size_t)b * TOKS * DIM_;
    for (int idx = tid; idx < TOKS*48; idx += 1024) {
      int r = idx / 48, c8 = (idx % 48) << 3;
      const float4* p = (const float4*)(xg + r*DIM_ + c8);
      float4 a0 = p[0], a1 = p[1];
      bf16x8 v;
      v[0]=(short)f2b(a0.x); v[1]=(short)f2b(a0.y); v[2]=(short)f2b(a0.z); v[3]=(short)f2b(a0.w);
      v[4]=(short)f2b(a1.x); v[5]=(short)f2b(a1.y); v[6]=(short)f2b(a1.z); v[7]=(short)f2b(a1.w);
      *(bf16x8*)&xA[r*SXA + c8] = v;
    }
    bf16x8 z = {0,0,0,0,0,0,0,0};
    for (int idx = tid; idx < 15*48; idx += 1024) {
      int r = 49 + idx / 48, c8 = (idx % 48) << 3;
      *(bf16x8*)&xA[r*SXA + c8] = z;
    }
  }
  __syncthreads();

  const f32x4 fz = {0.f, 0.f, 0.f, 0.f};

  for (int g = 0; g < 3; ++g) {
    const int hbase = g * 4;

    // ---- GEMM1: qkv for 4 heads. Wave = (ctile, mh): computes 16-col block
    // ctile of q, k, v over rows mh*32..mh*32+31. A-frags reused 3x.
    {
      const int cb = hbase*2 + ctile;
      const unsigned short* bq = w1p + (size_t)(cb*12)*512 + lane*8;
      const unsigned short* bk = bq + (size_t)(24*12)*512;
      const unsigned short* bv = bq + (size_t)(48*12)*512;
      f32x4 aq[2], ak[2], av[2];
      #pragma unroll
      for (int m = 0; m < 2; ++m) { aq[m]=fz; ak[m]=fz; av[m]=fz; }
      #pragma unroll
      for (int kk = 0; kk < 12; ++kk) {
        bf16x8 fq = *(const bf16x8*)(bq + kk*512);
        bf16x8 fk = *(const bf16x8*)(bk + kk*512);
        bf16x8 fv = *(const bf16x8*)(bv + kk*512);
        #pragma unroll
        for (int m = 0; m < 2; ++m) {
          bf16x8 a = *(const bf16x8*)&xA[((mh*2 + m)*16 + lr)*SXA + kk*32 + lg*8];
          aq[m] = __builtin_amdgcn_mfma_f32_16x16x32_bf16(a, fq, aq[m], 0, 0, 0);
          ak[m] = __builtin_amdgcn_mfma_f32_16x16x32_bf16(a, fk, ak[m], 0, 0, 0);
          av[m] = __builtin_amdgcn_mfma_f32_16x16x32_bf16(a, fv, av[m], 0, 0, 0);
        }
      }
      const float bsq = b1[cb*16 + lr];
      const float bsk = b1[(24 + cb)*16 + lr];
      const float bsv = b1[(48 + cb)*16 + lr];
      const int d128 = (ctile << 4) + lr;
      #pragma unroll
      for (int m = 0; m < 2; ++m) {
        #pragma unroll
        for (int j = 0; j < 4; ++j) {
          const int tok = (mh*2 + m)*16 + lg*4 + j;
          Q4[tok*SQK + d128]  = f2b((aq[m][j] + bsq) * 0.17677669529663687f);
          K4[tok*SQK + d128]  = f2b(ak[m][j] + bsk);
          Vt4[d128*SV + tok]  = f2b(av[m][j] + bsv);
        }
      }
    }
    __syncthreads();

    // ---- attention: 16 tasks = (head hl, q-block m0), one per wave.
    {
      const int hl = wv >> 2;
      const int h  = hbase + hl;
      const int qoff = hl * HDIM;
      const int m0 = (wv & 3) << 4;

      // hoist combined bias+mask loads (independent of QK^T)
      float c[4][4];
      const float* cp = cmb + ((size_t)(wi*NHEAD + h) << 12) + m0 + lr;
      #pragma unroll
      for (int nt = 0; nt < 4; ++nt)
        #pragma unroll
        for (int jj = 0; jj < 4; ++jj)
          c[nt][jj] = cp[(nt*16 + lg*4 + jj) << 6];

      // swapped QK^T: S^T[k][q] = mfma(A=K, B=Q); lane holds 16 k's of col q
      bf16x8 qa = *(const bf16x8*)&Q4[(m0 + lr)*SQK + qoff + lg*8];
      f32x4 S[4];
      #pragma unroll
      for (int nt = 0; nt < 4; ++nt) {
        bf16x8 kb = *(const bf16x8*)&K4[((nt<<4) + lr)*SQK + qoff + lg*8];
        S[nt] = __builtin_amdgcn_mfma_f32_16x16x32_bf16(kb, qa, fz, 0, 0, 0);
      }

      // softmax over k (lanes lr, lr+16, lr+32, lr+48 share column q)
      float p[4][4];
      float mx = -1e30f;
      #pragma unroll
      for (int nt = 0; nt < 4; ++nt)
        #pragma unroll
        for (int jj = 0; jj < 4; ++jj) {
          p[nt][jj] = S[nt][jj] + c[nt][jj];
          mx = fmaxf(mx, p[nt][jj]);
        }
      mx = fmaxf(mx, __shfl_xor(mx, 16));
      mx = fmaxf(mx, __shfl_xor(mx, 32));
      float sum = 0.f;
      #pragma unroll
      for (int nt = 0; nt < 4; ++nt)
        #pragma unroll
        for (int jj = 0; jj < 4; ++jj) {
          float e = __expf(p[nt][jj] - mx);
          p[nt][jj] = e; sum += e;
        }
      sum += __shfl_xor(sum, 16);
      sum += __shfl_xor(sum, 32);
      const float inv = 1.0f / sum;

      // pack P to bf16 pairs (per nt: (p0,p1),(p2,p3))
      unsigned pk[4][2];
      #pragma unroll
      for (int nt = 0; nt < 4; ++nt) {
        pk[nt][0] = (unsigned)f2b(p[nt][0]*inv) | ((unsigned)f2b(p[nt][1]*inv) << 16);
        pk[nt][1] = (unsigned)f2b(p[nt][2]*inv) | ((unsigned)f2b(p[nt][3]*inv) << 16);
      }

      // PV: O[q][d] = sum_k P^T[k][q] V[k][d]. Assemble A-frags (rows=q) by
      // cross-lg shuffles; shuffled register index is uniform (two-shfl+select).
      const int src0 = (lane & 15) + ((lane & 16) << 1);
      const int src1 = src0 + 16;
      const bool loH = lane < 32;   // lg<2 -> k-block 2kk, else 2kk+1
      f32x4 o0 = fz, o1 = fz;
      #pragma unroll
      for (int kk = 0; kk < 2; ++kk) {
        unsigned wA0 = __shfl(pk[2*kk][0], src0), wB0 = __shfl(pk[2*kk+1][0], src0);
        unsigned wA1 = __shfl(pk[2*kk][1], src0), wB1 = __shfl(pk[2*kk+1][1], src0);
        unsigned wA2 = __shfl(pk[2*kk][0], src1), wB2 = __shfl(pk[2*kk+1][0], src1);
        unsigned wA3 = __shfl(pk[2*kk][1], src1), wB3 = __shfl(pk[2*kk+1][1], src1);
        union { unsigned u[4]; bf16x8 v; } af;
        af.u[0] = loH ? wA0 : wB0;
        af.u[1] = loH ? wA1 : wB1;
        af.u[2] = loH ? wA2 : wB2;
        af.u[3] = loH ? wA3 : wB3;
        bf16x8 vb0 = *(const bf16x8*)&Vt4[(qoff + lr)*SV + kk*32 + lg*8];
        bf16x8 vb1 = *(const bf16x8*)&Vt4[(qoff + 16 + lr)*SV + kk*32 + lg*8];
        o0 = __builtin_amdgcn_mfma_f32_16x16x32_bf16(af.v, vb0, o0, 0, 0, 0);
        o1 = __builtin_amdgcn_mfma_f32_16x16x32_bf16(af.v, vb1, o1, 0, 0, 0);
      }
      const int ocol = h*HDIM + lr;
      #pragma unroll
      for (int j = 0; j < 4; ++j) {
        const int tok = m0 + lg*4 + j;
        Ob[tok*SXA + ocol]      = f2b(o0[j]);
        Ob[tok*SXA + ocol + 16] = f2b(o1[j]);
      }
    }
    __syncthreads();
  }

  // ---- GEMM2: out = O @ proj_w^T + proj_b. Wave = (ctile, mh); 3 col-tiles
  // (ctile, ctile+8, ctile+16) share this wave's 24 A-frags.
  {
    const unsigned short* bp0 = w2p + (size_t)(ctile*12)*512 + lane*8;
    const unsigned short* bp1 = bp0 + (size_t)(8*12)*512;
    const unsigned short* bp2 = bp0 + (size_t)(16*12)*512;
    f32x4 ac0[2], ac1[2], ac2[2];
    #pragma unroll
    for (int m = 0; m < 2; ++m) { ac0[m]=fz; ac1[m]=fz; ac2[m]=fz; }
    #pragma unroll
    for (int kk = 0; kk < 12; ++kk) {
      bf16x8 f0 = *(const bf16x8*)(bp0 + kk*512);
      bf16x8 f1 = *(const bf16x8*)(bp1 + kk*512);
      bf16x8 f2 = *(const bf16x8*)(bp2 + kk*512);
      #pragma unroll
      for (int m = 0; m < 2; ++m) {
        bf16x8 a = *(const bf16x8*)&Ob[((mh*2 + m)*16 + lr)*SXA + kk*32 + lg*8];
        ac0[m] = __builtin_amdgcn_mfma_f32_16x16x32_bf16(a, f0, ac0[m], 0, 0, 0);
        ac1[m] = __builtin_amdgcn_mfma_f32_16x16x32_bf16(a, f1, ac1[m], 0, 0, 0);
        ac2[m] = __builtin_amdgcn_mfma_f32_16x16x32_bf16(a, f2, ac2[m], 0, 0, 0);
      }
    }
    float* og = out + (size_t)b * TOKS * DIM_;
    #pragma unroll
    for (int ni = 0; ni < 3; ++ni) {
      const int col = ((ctile + ni*8) << 4) + lr;
      const float pb = b2[col];
      const f32x4* ac = ni == 0 ? ac0 : (ni == 1 ? ac1 : ac2);
      #pragma unroll
      for (int m = 0; m < 2; ++m)
        #pragma unroll
        for (int j = 0; j < 4; ++j) {
          const int tok = (mh*2 + m)*16 + lg*4 + j;
          if (tok < TOKS) og[tok*DIM_ + col] = ac[m][j] + pb;
        }
    }
  }
}

extern "C" void kernel_launch(void* const* d_in, const int* in_sizes, int n_in,
                              void* d_out, int out_size, void* d_ws, size_t ws_size,
                              hipStream_t stream) {
  const float* x      = (const float*)d_in[0];
  const float* mask   = (const float*)d_in[1];
  const float* qkv_w  = (const float*)d_in[2];
  const float* qkv_b  = (const float*)d_in[3];
  const float* proj_w = (const float*)d_in[4];
  const float* proj_b = (const float*)d_in[5];
  const float* rpb    = (const float*)d_in[6];
  float* out = (float*)d_out;

  if (ws_size < WS_NEEDED) return;  // refuse to fault on undersized workspace

  unsigned short* w1p = (unsigned short*)d_ws;
  unsigned short* w2p = w1p + W1E;
  float* cmb = (float*)(w2p + W2E);

  prep_kernel<<<(CMBE + 255)/256, 256, 0, stream>>>(qkv_w, proj_w, rpb, mask,
                                                    w1p, w2p, cmb);

  hipFuncSetAttribute((const void*)wattn_kernel,
                      hipFuncAttributeMaxDynamicSharedMemorySize, LDS_BYTES);
  wattn_kernel<<<4096, 1024, LDS_BYTES, stream>>>(x, w1p, qkv_b, w2p,
                                                  proj_b, cmb, out);
}